// Round 13
// baseline (39.604 us; speedup 1.0000x reference)
//
#include <hip/hip_runtime.h>
#include <hip/hip_bf16.h>

#define B_SZ  64
#define N_SZ  512
#define K_SZ  16
#define EMB   128
#define R_TOT (B_SZ * N_SZ)   // 32768 rows

typedef __attribute__((ext_vector_type(8))) short bf16x8;
typedef __attribute__((ext_vector_type(4))) float f32x4;

// XOR-swizzled u16 index into a [*][128]-u16 LDS tile (16B-unit granularity).
#define SWZ(row, col) ((((row) << 7)) + ((((col) >> 3) ^ ((row) & 15)) << 3) + ((col) & 7))

static __device__ __forceinline__ unsigned short f2bf(float x) {
    __hip_bfloat16 h = __float2bfloat16(x);   // RNE
    return *reinterpret_cast<unsigned short*>(&h);
}
static __device__ __forceinline__ float bf_lo(unsigned int v) {
    union { unsigned int u; float f; } c; c.u = v << 16; return c.f;
}
static __device__ __forceinline__ float bf_hi(unsigned int v) {
    union { unsigned int u; float f; } c; c.u = v & 0xFFFF0000u; return c.f;
}

// Fused: X = word@Wtop + bias (store bf16, pre-relu); Y = relu(X)@Wbot (store F32).
// 512 threads = 8 waves; wave w owns 16 output cols (acc[4][1]) -> ~half the VGPR
// state of the 4-wave version and 1/4 the redundant W-fragment build (64 vs 256
// load+cvt chains/thread). B-fragments direct from W_enc (coalesced, L2-hot).
// Y stored as f32 so the gather needs NO bf16 unpack (pk_add on float2).
// First 16 blocks zero d_out. XCD-affine map: batch b's blocks on XCD b&7.
__global__ __launch_bounds__(512, 4) void dual_gemm(const float* __restrict__ word,
                                                    const float* __restrict__ W_enc,
                                                    const float* __restrict__ bias,
                                                    unsigned short* __restrict__ Xb,
                                                    float* __restrict__ Yf,
                                                    float* __restrict__ out)
{
    __shared__ unsigned short sA0[64 * EMB];   // 16 KB, bf16(word) tile, swizzled
    __shared__ unsigned short sA1[64 * EMB];   // 16 KB, relu(X) tile, swizzled
    const int tid = threadIdx.x;

    const int bid    = blockIdx.x;
    const int xcd    = bid & 7;
    const int j      = bid >> 3;
    const int b      = xcd + 8 * (j & 7);
    const int rchunk = j >> 3;
    const int block_row = b * N_SZ + rchunk * 64;

    if (bid < 16) out[bid * 512 + tid] = 0.f;      // zero the 8192-float accumulator

    for (int i = tid; i < 2048; i += 512) {        // A tile f32 -> bf16 (4 float4/thread)
        int r = i >> 5, c4 = i & 31;
        float4 v = ((const float4*)(word + (size_t)(block_row + r) * EMB))[c4];
        unsigned short o[4] = { f2bf(v.x), f2bf(v.y), f2bf(v.z), f2bf(v.w) };
        *(uint2*)&sA0[SWZ(r, c4 * 4)] = *(uint2*)o;
    }

    const int lane  = tid & 63;
    const int w     = tid >> 6;                 // wave 0..7
    const int l15   = lane & 15;
    const int g     = lane >> 4;                // 0..3
    const int col   = w * 16 + l15;             // this thread's single output col

    // B fragments for GEMM1 straight from W_enc (16-lane groups -> 64B segments)
    bf16x8 bfr[4];
    #pragma unroll
    for (int ks = 0; ks < 4; ++ks) {
        unsigned short t[8];
        #pragma unroll
        for (int jj = 0; jj < 8; ++jj)
            t[jj] = f2bf(W_enc[(size_t)(ks * 32 + g * 8 + jj) * EMB + col]);
        bfr[ks] = *(bf16x8*)t;
    }

    f32x4 acc[4];
    #pragma unroll
    for (int mb = 0; mb < 4; ++mb) acc[mb] = (f32x4){0.f, 0.f, 0.f, 0.f};

    __syncthreads();   // sA0 staged

    // ---- GEMM1: sA0 @ Wtop (cols w*16..w*16+15) ----
    #pragma unroll
    for (int ks = 0; ks < 4; ++ks) {
        bf16x8 a[4];
        #pragma unroll
        for (int mb = 0; mb < 4; ++mb)
            a[mb] = *(const bf16x8*)&sA0[SWZ(mb * 16 + l15, ks * 32 + g * 8)];
        #pragma unroll
        for (int mb = 0; mb < 4; ++mb)
            acc[mb] = __builtin_amdgcn_mfma_f32_16x16x32_bf16(a[mb], bfr[ks], acc[mb], 0, 0, 0);
    }

    // epilogue 1: X = acc + bias; store Xb (pre-relu, bf16); relu into sA1
    {
        const float bv = bias[col];
        #pragma unroll
        for (int mb = 0; mb < 4; ++mb) {
            #pragma unroll
            for (int r = 0; r < 4; ++r) {
                const int row_l = mb * 16 + g * 4 + r;
                float x = acc[mb][r] + bv;
                Xb[(size_t)(block_row + row_l) * EMB + col] = f2bf(x);
                sA1[SWZ(row_l, col)] = f2bf(fmaxf(x, 0.f));
            }
            acc[mb] = (f32x4){0.f, 0.f, 0.f, 0.f};
        }
    }
    __syncthreads();   // sA1 complete

    // B fragments for GEMM2 (Wbot rows 128..255, L2-hot)
    bf16x8 bfr2[4];
    #pragma unroll
    for (int ks = 0; ks < 4; ++ks) {
        unsigned short t[8];
        #pragma unroll
        for (int jj = 0; jj < 8; ++jj)
            t[jj] = f2bf(W_enc[(size_t)(128 + ks * 32 + g * 8 + jj) * EMB + col]);
        bfr2[ks] = *(bf16x8*)t;
    }

    // ---- GEMM2: relu(X) @ Wbot ----
    #pragma unroll
    for (int ks = 0; ks < 4; ++ks) {
        bf16x8 a[4];
        #pragma unroll
        for (int mb = 0; mb < 4; ++mb)
            a[mb] = *(const bf16x8*)&sA1[SWZ(mb * 16 + l15, ks * 32 + g * 8)];
        #pragma unroll
        for (int mb = 0; mb < 4; ++mb)
            acc[mb] = __builtin_amdgcn_mfma_f32_16x16x32_bf16(a[mb], bfr2[ks], acc[mb], 0, 0, 0);
    }
    // epilogue 2: Y stored as f32 directly from the accumulator (no cvt)
    #pragma unroll
    for (int mb = 0; mb < 4; ++mb)
        #pragma unroll
        for (int r = 0; r < 4; ++r) {
            const int row_l = mb * 16 + g * 4 + r;
            Yf[(size_t)(block_row + row_l) * EMB + col] = acc[mb][r];
        }
}

// Per (b,chunk): wave g sums mask*relu(X + mean_k Y[nb]) over 8 n's; lane owns
// cols 2*lane, 2*lane+1. Y is f32: float2 loads, v_pk_add_f32 accumulate — zero
// unpack VALU. 32-bit offsets from wave-uniform bases. In-block reduce ->
// chunk_pool, chunk_pool@W2 -> atomicAdd into out[b]. Batch b on XCD b&7.
__global__ __launch_bounds__(256) void gather_pool_w2(const unsigned short* __restrict__ Xb,
                                                      const float* __restrict__ Yf,
                                                      const int*   __restrict__ nbr,
                                                      const float* __restrict__ mask,
                                                      const float* __restrict__ W2,
                                                      float* __restrict__ out)
{
    const int bid   = blockIdx.x;
    const int xcd   = bid & 7;
    const int rest  = bid >> 3;
    const int chunk = rest & 15;
    const int b     = (rest >> 4) * 8 + xcd;
    const int g     = threadIdx.x >> 6;        // 4 waves
    const int lane  = threadIdx.x & 63;

    const float2* Yw = (const float2*)(Yf + (size_t)b * N_SZ * EMB);   // wave-uniform base
    const unsigned int* Xw = (const unsigned int*)Xb;                  // wave-uniform base

    float s0 = 0.f, s1 = 0.f;
    for (int nn = 0; nn < 8; ++nn) {
        const int n = chunk * 32 + g * 8 + nn;                // wave-uniform
        const unsigned int base = (unsigned int)(b * N_SZ + n);
        const int* idx = nbr + (size_t)base * K_SZ;
        int id[K_SZ];
        #pragma unroll
        for (int k = 0; k < K_SZ; ++k) id[k] = idx[k];

        float2 aa = {0.f, 0.f}, ab = {0.f, 0.f};              // even/odd chains
        #pragma unroll
        for (int k = 0; k < K_SZ; k += 2) {
            float2 v0 = Yw[(((unsigned int)id[k])     << 6) + lane];
            float2 v1 = Yw[(((unsigned int)id[k + 1]) << 6) + lane];
            aa.x += v0.x; aa.y += v0.y;                       // v_pk_add_f32
            ab.x += v1.x; ab.y += v1.y;
        }
        unsigned int xv = Xw[(base << 6) + lane];
        const float m = mask[base];
        s0 += fmaxf(bf_lo(xv) + (aa.x + ab.x) * 0.0625f, 0.f) * m;
        s1 += fmaxf(bf_hi(xv) + (aa.y + ab.y) * 0.0625f, 0.f) * m;
    }

    // in-block reduce: 4 wave-partials -> chunk_pool[128] in sred[0][*]
    __shared__ float sred[4][EMB];
    const int e0 = lane * 2;
    sred[g][e0]     = s0;
    sred[g][e0 + 1] = s1;
    __syncthreads();
    const int t = threadIdx.x;
    if (t < EMB)
        sred[0][t] = sred[0][t] + sred[1][t] + sred[2][t] + sred[3][t];
    __syncthreads();

    // chunk_pool @ W2 -> atomicAdd into out[b][*]
    if (t < EMB) {
        float r = 0.f;
        #pragma unroll 8
        for (int f = 0; f < EMB; ++f) r += sred[0][f] * W2[f * EMB + t];
        atomicAdd(&out[b * EMB + t], r);
    }
}

extern "C" void kernel_launch(void* const* d_in, const int* in_sizes, int n_in,
                              void* d_out, int out_size, void* d_ws, size_t ws_size,
                              hipStream_t stream)
{
    const float* word  = (const float*)d_in[0];
    const int*   nbr   = (const int*)  d_in[1];
    const float* mask  = (const float*)d_in[2];
    const float* W_enc = (const float*)d_in[3];
    const float* b_enc = (const float*)d_in[4];
    const float* W2    = (const float*)d_in[5];
    float* out = (float*)d_out;

    unsigned short* Xb = (unsigned short*)d_ws;          // [32768][128] bf16, 8 MB
    float*          Yf = (float*)(Xb + (size_t)R_TOT * EMB); // [32768][128] f32, 16 MB

    dual_gemm     <<<R_TOT / 64, 512, 0, stream>>>(word, W_enc, b_enc, Xb, Yf, out);
    gather_pool_w2<<<B_SZ * 16,  256, 0, stream>>>(Xb, Yf, nbr, mask, W2, out);
}

// Round 14
// 34.002 us; speedup vs baseline: 1.1648x; 1.1648x over previous
//
#include <hip/hip_runtime.h>
#include <hip/hip_bf16.h>

#define B_SZ  64
#define N_SZ  512
#define K_SZ  16
#define EMB   128
#define R_TOT (B_SZ * N_SZ)   // 32768 rows

typedef __attribute__((ext_vector_type(8))) short bf16x8;
typedef __attribute__((ext_vector_type(4))) float f32x4;

// XOR-swizzled u16 index into a [*][128]-u16 LDS tile (16B-unit granularity).
#define SWZ(row, col) ((((row) << 7)) + ((((col) >> 3) ^ ((row) & 15)) << 3) + ((col) & 7))

static __device__ __forceinline__ unsigned short f2bf(float x) {
    __hip_bfloat16 h = __float2bfloat16(x);   // RNE
    return *reinterpret_cast<unsigned short*>(&h);
}
static __device__ __forceinline__ float bf_lo(unsigned int v) {
    union { unsigned int u; float f; } c; c.u = v << 16; return c.f;
}
static __device__ __forceinline__ float bf_hi(unsigned int v) {
    union { unsigned int u; float f; } c; c.u = v & 0xFFFF0000u; return c.f;
}

// ==== dual_gemm: exact R12 version (best measured) ====
// X = word@Wtop + bias (store bf16, pre-relu); Y = relu(X)@Wbot (store bf16).
// B-fragments direct from W_enc (coalesced scalar loads, L2-hot); bfr2 loaded
// after the barrier to cut held VGPRs; __launch_bounds__(256,3) -> 3 waves/SIMD.
// First 32 blocks zero d_out. XCD-affine map: batch b's blocks on XCD b&7.
__global__ __launch_bounds__(256, 3) void dual_gemm(const float* __restrict__ word,
                                                    const float* __restrict__ W_enc,
                                                    const float* __restrict__ bias,
                                                    unsigned short* __restrict__ Xb,
                                                    unsigned short* __restrict__ Yb,
                                                    float* __restrict__ out)
{
    __shared__ unsigned short sA0[64 * EMB];   // 16 KB, bf16(word) tile, swizzled
    __shared__ unsigned short sA1[64 * EMB];   // 16 KB, relu(X) tile, swizzled
    const int tid = threadIdx.x;

    const int bid    = blockIdx.x;
    const int xcd    = bid & 7;
    const int j      = bid >> 3;
    const int b      = xcd + 8 * (j & 7);
    const int rchunk = j >> 3;
    const int block_row = b * N_SZ + rchunk * 64;

    if (bid < 32) out[bid * 256 + tid] = 0.f;

    for (int i = tid; i < 2048; i += 256) {
        int r = i >> 5, c4 = i & 31;
        float4 v = ((const float4*)(word + (size_t)(block_row + r) * EMB))[c4];
        unsigned short o[4] = { f2bf(v.x), f2bf(v.y), f2bf(v.z), f2bf(v.w) };
        *(uint2*)&sA0[SWZ(r, c4 * 4)] = *(uint2*)o;
    }

    const int lane  = tid & 63;
    const int w     = tid >> 6;
    const int l15   = lane & 15;
    const int g     = lane >> 4;
    const int ncol0 = w * 32;

    bf16x8 bfr[2][4];
    #pragma unroll
    for (int nb = 0; nb < 2; ++nb) {
        const int col = ncol0 + nb * 16 + l15;
        #pragma unroll
        for (int ks = 0; ks < 4; ++ks) {
            unsigned short t[8];
            #pragma unroll
            for (int jj = 0; jj < 8; ++jj)
                t[jj] = f2bf(W_enc[(size_t)(ks * 32 + g * 8 + jj) * EMB + col]);
            bfr[nb][ks] = *(bf16x8*)t;
        }
    }

    f32x4 acc[4][2];
    #pragma unroll
    for (int mb = 0; mb < 4; ++mb)
        #pragma unroll
        for (int nb = 0; nb < 2; ++nb)
            acc[mb][nb] = (f32x4){0.f, 0.f, 0.f, 0.f};

    __syncthreads();

    // ---- GEMM1: sA0 @ Wtop ----
    #pragma unroll
    for (int ks = 0; ks < 4; ++ks) {
        bf16x8 a[4];
        #pragma unroll
        for (int mb = 0; mb < 4; ++mb)
            a[mb] = *(const bf16x8*)&sA0[SWZ(mb * 16 + l15, ks * 32 + g * 8)];
        #pragma unroll
        for (int mb = 0; mb < 4; ++mb)
            #pragma unroll
            for (int nb = 0; nb < 2; ++nb)
                acc[mb][nb] = __builtin_amdgcn_mfma_f32_16x16x32_bf16(a[mb], bfr[nb][ks], acc[mb][nb], 0, 0, 0);
    }

    // epilogue 1: X = acc + bias; store Xb (pre-relu); relu into sA1
    #pragma unroll
    for (int mb = 0; mb < 4; ++mb) {
        #pragma unroll
        for (int nb = 0; nb < 2; ++nb) {
            const int col = ncol0 + nb * 16 + l15;
            const float bv = bias[col];
            #pragma unroll
            for (int r = 0; r < 4; ++r) {
                const int row_l = mb * 16 + g * 4 + r;
                float x = acc[mb][nb][r] + bv;
                Xb[(size_t)(block_row + row_l) * EMB + col] = f2bf(x);
                sA1[SWZ(row_l, col)] = f2bf(fmaxf(x, 0.f));
            }
            acc[mb][nb] = (f32x4){0.f, 0.f, 0.f, 0.f};
        }
    }
    __syncthreads();

    // B fragments for GEMM2 (Wbot, L2-hot) — loaded here to cut VGPR
    bf16x8 bfr2[2][4];
    #pragma unroll
    for (int nb = 0; nb < 2; ++nb) {
        const int col = ncol0 + nb * 16 + l15;
        #pragma unroll
        for (int ks = 0; ks < 4; ++ks) {
            unsigned short t[8];
            #pragma unroll
            for (int jj = 0; jj < 8; ++jj)
                t[jj] = f2bf(W_enc[(size_t)(128 + ks * 32 + g * 8 + jj) * EMB + col]);
            bfr2[nb][ks] = *(bf16x8*)t;
        }
    }

    // ---- GEMM2: relu(X) @ Wbot ----
    #pragma unroll
    for (int ks = 0; ks < 4; ++ks) {
        bf16x8 a[4];
        #pragma unroll
        for (int mb = 0; mb < 4; ++mb)
            a[mb] = *(const bf16x8*)&sA1[SWZ(mb * 16 + l15, ks * 32 + g * 8)];
        #pragma unroll
        for (int mb = 0; mb < 4; ++mb)
            #pragma unroll
            for (int nb = 0; nb < 2; ++nb)
                acc[mb][nb] = __builtin_amdgcn_mfma_f32_16x16x32_bf16(a[mb], bfr2[nb][ks], acc[mb][nb], 0, 0, 0);
    }
    #pragma unroll
    for (int mb = 0; mb < 4; ++mb)
        #pragma unroll
        for (int nb = 0; nb < 2; ++nb) {
            const int col = ncol0 + nb * 16 + l15;
            #pragma unroll
            for (int r = 0; r < 4; ++r) {
                const int row_l = mb * 16 + g * 4 + r;
                Yb[(size_t)(block_row + row_l) * EMB + col] = f2bf(acc[mb][nb][r]);
            }
        }
}

// ==== gather: R12 arithmetic, 2x finer grid for full wave occupancy ====
// 2048 blocks (vs 1024): block = (b, chunk of 16 n); wave g handles 4 n's.
// 8192 waves = 100% of the 256-CU wave capacity (R11 probe showed 40% occ).
// 32-bit offsets from wave-uniform bases; even/odd split accumulators.
// In-block reduce -> chunk_pool[128] -> @W2 -> atomicAdd into out[b].
// XCD map: batch b on XCD b&7 (matches dual_gemm's producer map).
__global__ __launch_bounds__(256) void gather_pool_w2(const unsigned short* __restrict__ Xb,
                                                      const unsigned short* __restrict__ Yb,
                                                      const int*   __restrict__ nbr,
                                                      const float* __restrict__ mask,
                                                      const float* __restrict__ W2,
                                                      float* __restrict__ out)
{
    const int bid   = blockIdx.x;                  // 0..2047
    const int xcd   = bid & 7;
    const int chunk = (bid >> 3) & 31;             // 32 chunks of 16 n
    const int b     = (bid >> 8) * 8 + xcd;        // 0..63, b&7 == xcd
    const int g     = threadIdx.x >> 6;            // 4 waves
    const int lane  = threadIdx.x & 63;

    const unsigned int* Yw = (const unsigned int*)(Yb + (size_t)b * N_SZ * EMB); // uniform
    const unsigned int* Xw = (const unsigned int*)Xb;                            // uniform

    float s0 = 0.f, s1 = 0.f;
    for (int nn = 0; nn < 4; ++nn) {
        const int n = chunk * 16 + g * 4 + nn;     // wave-uniform
        const unsigned int base = (unsigned int)(b * N_SZ + n);
        const int* idx = nbr + (size_t)base * K_SZ;
        int id[K_SZ];
        #pragma unroll
        for (int k = 0; k < K_SZ; ++k) id[k] = idx[k];

        float a0a = 0.f, a0b = 0.f, a1a = 0.f, a1b = 0.f;
        #pragma unroll
        for (int k = 0; k < K_SZ; k += 2) {
            unsigned int v0 = Yw[(((unsigned int)id[k])     << 6) + lane];
            unsigned int v1 = Yw[(((unsigned int)id[k + 1]) << 6) + lane];
            a0a += bf_lo(v0); a1a += bf_hi(v0);
            a0b += bf_lo(v1); a1b += bf_hi(v1);
        }
        unsigned int xv = Xw[(base << 6) + lane];
        const float m = mask[base];
        s0 += fmaxf(bf_lo(xv) + (a0a + a0b) * 0.0625f, 0.f) * m;
        s1 += fmaxf(bf_hi(xv) + (a1a + a1b) * 0.0625f, 0.f) * m;
    }

    // in-block reduce: 4 wave-partials -> chunk_pool[128] in sred[0][*]
    __shared__ float sred[4][EMB];
    const int e0 = lane * 2;
    sred[g][e0]     = s0;
    sred[g][e0 + 1] = s1;
    __syncthreads();
    const int t = threadIdx.x;
    if (t < EMB)
        sred[0][t] = sred[0][t] + sred[1][t] + sred[2][t] + sred[3][t];
    __syncthreads();

    // chunk_pool @ W2 -> atomicAdd into out[b][*]
    if (t < EMB) {
        float r = 0.f;
        #pragma unroll 8
        for (int f = 0; f < EMB; ++f) r += sred[0][f] * W2[f * EMB + t];
        atomicAdd(&out[b * EMB + t], r);
    }
}

extern "C" void kernel_launch(void* const* d_in, const int* in_sizes, int n_in,
                              void* d_out, int out_size, void* d_ws, size_t ws_size,
                              hipStream_t stream)
{
    const float* word  = (const float*)d_in[0];
    const int*   nbr   = (const int*)  d_in[1];
    const float* mask  = (const float*)d_in[2];
    const float* W_enc = (const float*)d_in[3];
    const float* b_enc = (const float*)d_in[4];
    const float* W2    = (const float*)d_in[5];
    float* out = (float*)d_out;

    unsigned short* Xb = (unsigned short*)d_ws;          // [32768][128] bf16, 8 MB
    unsigned short* Yb = Xb + (size_t)R_TOT * EMB;       // 8 MB

    dual_gemm     <<<R_TOT / 64, 256, 0, stream>>>(word, W_enc, b_enc, Xb, Yb, out);
    gather_pool_w2<<<B_SZ * 32,  256, 0, stream>>>(Xb, Yb, nbr, mask, W2, out);
}

// Round 15
// 32.546 us; speedup vs baseline: 1.2169x; 1.0448x over previous
//
#include <hip/hip_runtime.h>
#include <hip/hip_bf16.h>

#define B_SZ  64
#define N_SZ  512
#define K_SZ  16
#define EMB   128
#define R_TOT (B_SZ * N_SZ)   // 32768 rows

typedef __attribute__((ext_vector_type(8))) short bf16x8;
typedef __attribute__((ext_vector_type(4))) float f32x4;

// XOR-swizzled u16 index into a [*][128]-u16 LDS tile (16B-unit granularity).
#define SWZ(row, col) ((((row) << 7)) + ((((col) >> 3) ^ ((row) & 15)) << 3) + ((col) & 7))

static __device__ __forceinline__ unsigned short f2bf(float x) {
    __hip_bfloat16 h = __float2bfloat16(x);   // RNE
    return *reinterpret_cast<unsigned short*>(&h);
}
static __device__ __forceinline__ float bf_lo(unsigned int v) {
    union { unsigned int u; float f; } c; c.u = v << 16; return c.f;
}
static __device__ __forceinline__ float bf_hi(unsigned int v) {
    union { unsigned int u; float f; } c; c.u = v & 0xFFFF0000u; return c.f;
}

// ==== dual_gemm: exact R12 version (best measured) ====
// X = word@Wtop + bias (store bf16, pre-relu); Y = relu(X)@Wbot (store bf16).
// B-fragments direct from W_enc (coalesced scalar loads, L2-hot); bfr2 loaded
// after the barrier to cut held VGPRs; __launch_bounds__(256,3) -> 3 waves/SIMD.
// First 32 blocks zero d_out. XCD-affine map: batch b's blocks on XCD b&7.
__global__ __launch_bounds__(256, 3) void dual_gemm(const float* __restrict__ word,
                                                    const float* __restrict__ W_enc,
                                                    const float* __restrict__ bias,
                                                    unsigned short* __restrict__ Xb,
                                                    unsigned short* __restrict__ Yb,
                                                    float* __restrict__ out)
{
    __shared__ unsigned short sA0[64 * EMB];   // 16 KB, bf16(word) tile, swizzled
    __shared__ unsigned short sA1[64 * EMB];   // 16 KB, relu(X) tile, swizzled
    const int tid = threadIdx.x;

    const int bid    = blockIdx.x;
    const int xcd    = bid & 7;
    const int j      = bid >> 3;
    const int b      = xcd + 8 * (j & 7);
    const int rchunk = j >> 3;
    const int block_row = b * N_SZ + rchunk * 64;

    if (bid < 32) out[bid * 256 + tid] = 0.f;

    for (int i = tid; i < 2048; i += 256) {
        int r = i >> 5, c4 = i & 31;
        float4 v = ((const float4*)(word + (size_t)(block_row + r) * EMB))[c4];
        unsigned short o[4] = { f2bf(v.x), f2bf(v.y), f2bf(v.z), f2bf(v.w) };
        *(uint2*)&sA0[SWZ(r, c4 * 4)] = *(uint2*)o;
    }

    const int lane  = tid & 63;
    const int w     = tid >> 6;
    const int l15   = lane & 15;
    const int g     = lane >> 4;
    const int ncol0 = w * 32;

    bf16x8 bfr[2][4];
    #pragma unroll
    for (int nb = 0; nb < 2; ++nb) {
        const int col = ncol0 + nb * 16 + l15;
        #pragma unroll
        for (int ks = 0; ks < 4; ++ks) {
            unsigned short t[8];
            #pragma unroll
            for (int jj = 0; jj < 8; ++jj)
                t[jj] = f2bf(W_enc[(size_t)(ks * 32 + g * 8 + jj) * EMB + col]);
            bfr[nb][ks] = *(bf16x8*)t;
        }
    }

    f32x4 acc[4][2];
    #pragma unroll
    for (int mb = 0; mb < 4; ++mb)
        #pragma unroll
        for (int nb = 0; nb < 2; ++nb)
            acc[mb][nb] = (f32x4){0.f, 0.f, 0.f, 0.f};

    __syncthreads();

    // ---- GEMM1: sA0 @ Wtop ----
    #pragma unroll
    for (int ks = 0; ks < 4; ++ks) {
        bf16x8 a[4];
        #pragma unroll
        for (int mb = 0; mb < 4; ++mb)
            a[mb] = *(const bf16x8*)&sA0[SWZ(mb * 16 + l15, ks * 32 + g * 8)];
        #pragma unroll
        for (int mb = 0; mb < 4; ++mb)
            #pragma unroll
            for (int nb = 0; nb < 2; ++nb)
                acc[mb][nb] = __builtin_amdgcn_mfma_f32_16x16x32_bf16(a[mb], bfr[nb][ks], acc[mb][nb], 0, 0, 0);
    }

    // epilogue 1: X = acc + bias; store Xb (pre-relu); relu into sA1
    #pragma unroll
    for (int mb = 0; mb < 4; ++mb) {
        #pragma unroll
        for (int nb = 0; nb < 2; ++nb) {
            const int col = ncol0 + nb * 16 + l15;
            const float bv = bias[col];
            #pragma unroll
            for (int r = 0; r < 4; ++r) {
                const int row_l = mb * 16 + g * 4 + r;
                float x = acc[mb][nb][r] + bv;
                Xb[(size_t)(block_row + row_l) * EMB + col] = f2bf(x);
                sA1[SWZ(row_l, col)] = f2bf(fmaxf(x, 0.f));
            }
            acc[mb][nb] = (f32x4){0.f, 0.f, 0.f, 0.f};
        }
    }
    __syncthreads();

    // B fragments for GEMM2 (Wbot, L2-hot) — loaded here to cut VGPR
    bf16x8 bfr2[2][4];
    #pragma unroll
    for (int nb = 0; nb < 2; ++nb) {
        const int col = ncol0 + nb * 16 + l15;
        #pragma unroll
        for (int ks = 0; ks < 4; ++ks) {
            unsigned short t[8];
            #pragma unroll
            for (int jj = 0; jj < 8; ++jj)
                t[jj] = f2bf(W_enc[(size_t)(128 + ks * 32 + g * 8 + jj) * EMB + col]);
            bfr2[nb][ks] = *(bf16x8*)t;
        }
    }

    // ---- GEMM2: relu(X) @ Wbot ----
    #pragma unroll
    for (int ks = 0; ks < 4; ++ks) {
        bf16x8 a[4];
        #pragma unroll
        for (int mb = 0; mb < 4; ++mb)
            a[mb] = *(const bf16x8*)&sA1[SWZ(mb * 16 + l15, ks * 32 + g * 8)];
        #pragma unroll
        for (int mb = 0; mb < 4; ++mb)
            #pragma unroll
            for (int nb = 0; nb < 2; ++nb)
                acc[mb][nb] = __builtin_amdgcn_mfma_f32_16x16x32_bf16(a[mb], bfr2[nb][ks], acc[mb][nb], 0, 0, 0);
    }
    #pragma unroll
    for (int mb = 0; mb < 4; ++mb)
        #pragma unroll
        for (int nb = 0; nb < 2; ++nb) {
            const int col = ncol0 + nb * 16 + l15;
            #pragma unroll
            for (int r = 0; r < 4; ++r) {
                const int row_l = mb * 16 + g * 4 + r;
                Yb[(size_t)(block_row + row_l) * EMB + col] = f2bf(acc[mb][nb][r]);
            }
        }
}

// ==== gather: exact R12 structure (1024 blocks, 8 n/wave) + nn-loop unroll 2 ====
// Wave g sums mask*relu(X + mean_k Y[nb]) over 8 n's; 32-bit offsets from
// wave-uniform bases; even/odd split accumulators. #pragma unroll 2 doubles the
// independent load chains in flight (R11 probe: 43% of issue slots latency-idle).
// In-block reduce -> chunk_pool[128] -> @W2 -> atomicAdd into out[b].
// XCD map: batch b on XCD b&7 (matches dual_gemm's producer map).
__global__ __launch_bounds__(256) void gather_pool_w2(const unsigned short* __restrict__ Xb,
                                                      const unsigned short* __restrict__ Yb,
                                                      const int*   __restrict__ nbr,
                                                      const float* __restrict__ mask,
                                                      const float* __restrict__ W2,
                                                      float* __restrict__ out)
{
    const int bid   = blockIdx.x;
    const int xcd   = bid & 7;
    const int rest  = bid >> 3;
    const int chunk = rest & 15;
    const int b     = (rest >> 4) * 8 + xcd;
    const int g     = threadIdx.x >> 6;        // 4 waves
    const int lane  = threadIdx.x & 63;

    const unsigned int* Yw = (const unsigned int*)(Yb + (size_t)b * N_SZ * EMB); // uniform
    const unsigned int* Xw = (const unsigned int*)Xb;                            // uniform

    float s0 = 0.f, s1 = 0.f;
    #pragma unroll 2
    for (int nn = 0; nn < 8; ++nn) {
        const int n = chunk * 32 + g * 8 + nn;                // wave-uniform
        const unsigned int base = (unsigned int)(b * N_SZ + n);
        const int* idx = nbr + (size_t)base * K_SZ;
        int id[K_SZ];
        #pragma unroll
        for (int k = 0; k < K_SZ; ++k) id[k] = idx[k];

        float a0a = 0.f, a0b = 0.f, a1a = 0.f, a1b = 0.f;
        #pragma unroll
        for (int k = 0; k < K_SZ; k += 2) {
            unsigned int v0 = Yw[(((unsigned int)id[k])     << 6) + lane];
            unsigned int v1 = Yw[(((unsigned int)id[k + 1]) << 6) + lane];
            a0a += bf_lo(v0); a1a += bf_hi(v0);
            a0b += bf_lo(v1); a1b += bf_hi(v1);
        }
        unsigned int xv = Xw[(base << 6) + lane];
        const float m = mask[base];
        s0 += fmaxf(bf_lo(xv) + (a0a + a0b) * 0.0625f, 0.f) * m;
        s1 += fmaxf(bf_hi(xv) + (a1a + a1b) * 0.0625f, 0.f) * m;
    }

    // in-block reduce: 4 wave-partials -> chunk_pool[128] in sred[0][*]
    __shared__ float sred[4][EMB];
    const int e0 = lane * 2;
    sred[g][e0]     = s0;
    sred[g][e0 + 1] = s1;
    __syncthreads();
    const int t = threadIdx.x;
    if (t < EMB)
        sred[0][t] = sred[0][t] + sred[1][t] + sred[2][t] + sred[3][t];
    __syncthreads();

    // chunk_pool @ W2 -> atomicAdd into out[b][*]
    if (t < EMB) {
        float r = 0.f;
        #pragma unroll 8
        for (int f = 0; f < EMB; ++f) r += sred[0][f] * W2[f * EMB + t];
        atomicAdd(&out[b * EMB + t], r);
    }
}

extern "C" void kernel_launch(void* const* d_in, const int* in_sizes, int n_in,
                              void* d_out, int out_size, void* d_ws, size_t ws_size,
                              hipStream_t stream)
{
    const float* word  = (const float*)d_in[0];
    const int*   nbr   = (const int*)  d_in[1];
    const float* mask  = (const float*)d_in[2];
    const float* W_enc = (const float*)d_in[3];
    const float* b_enc = (const float*)d_in[4];
    const float* W2    = (const float*)d_in[5];
    float* out = (float*)d_out;

    unsigned short* Xb = (unsigned short*)d_ws;          // [32768][128] bf16, 8 MB
    unsigned short* Yb = Xb + (size_t)R_TOT * EMB;       // 8 MB

    dual_gemm     <<<R_TOT / 64, 256, 0, stream>>>(word, W_enc, b_enc, Xb, Yb, out);
    gather_pool_w2<<<B_SZ * 16,  256, 0, stream>>>(Xb, Yb, nbr, mask, W2, out);
}

// Round 16
// 30.670 us; speedup vs baseline: 1.2913x; 1.0612x over previous
//
#include <hip/hip_runtime.h>
#include <hip/hip_bf16.h>

#define B_SZ  64
#define N_SZ  512
#define K_SZ  16
#define EMB   128
#define R_TOT (B_SZ * N_SZ)   // 32768 rows

typedef __attribute__((ext_vector_type(8))) short bf16x8;
typedef __attribute__((ext_vector_type(4))) float f32x4;

// XOR-swizzled u16 index into a [*][128]-u16 LDS tile (16B-unit granularity).
#define SWZ(row, col) ((((row) << 7)) + ((((col) >> 3) ^ ((row) & 15)) << 3) + ((col) & 7))

static __device__ __forceinline__ unsigned short f2bf(float x) {
    __hip_bfloat16 h = __float2bfloat16(x);   // RNE
    return *reinterpret_cast<unsigned short*>(&h);
}
static __device__ __forceinline__ float bf_lo(unsigned int v) {
    union { unsigned int u; float f; } c; c.u = v << 16; return c.f;
}
static __device__ __forceinline__ float bf_hi(unsigned int v) {
    union { unsigned int u; float f; } c; c.u = v & 0xFFFF0000u; return c.f;
}

// ==== dual_gemm: exact R12/R15 version (best measured) ====
// X = word@Wtop + bias (store bf16, pre-relu); Y = relu(X)@Wbot (store bf16).
// B-fragments direct from W_enc (coalesced scalar loads, L2-hot); bfr2 loaded
// after the barrier to cut held VGPRs; __launch_bounds__(256,3) -> 3 waves/SIMD.
// First 32 blocks zero d_out. XCD-affine map: batch b's blocks on XCD b&7.
__global__ __launch_bounds__(256, 3) void dual_gemm(const float* __restrict__ word,
                                                    const float* __restrict__ W_enc,
                                                    const float* __restrict__ bias,
                                                    unsigned short* __restrict__ Xb,
                                                    unsigned short* __restrict__ Yb,
                                                    float* __restrict__ out)
{
    __shared__ unsigned short sA0[64 * EMB];   // 16 KB, bf16(word) tile, swizzled
    __shared__ unsigned short sA1[64 * EMB];   // 16 KB, relu(X) tile, swizzled
    const int tid = threadIdx.x;

    const int bid    = blockIdx.x;
    const int xcd    = bid & 7;
    const int j      = bid >> 3;
    const int b      = xcd + 8 * (j & 7);
    const int rchunk = j >> 3;
    const int block_row = b * N_SZ + rchunk * 64;

    if (bid < 32) out[bid * 256 + tid] = 0.f;

    for (int i = tid; i < 2048; i += 256) {
        int r = i >> 5, c4 = i & 31;
        float4 v = ((const float4*)(word + (size_t)(block_row + r) * EMB))[c4];
        unsigned short o[4] = { f2bf(v.x), f2bf(v.y), f2bf(v.z), f2bf(v.w) };
        *(uint2*)&sA0[SWZ(r, c4 * 4)] = *(uint2*)o;
    }

    const int lane  = tid & 63;
    const int w     = tid >> 6;
    const int l15   = lane & 15;
    const int g     = lane >> 4;
    const int ncol0 = w * 32;

    bf16x8 bfr[2][4];
    #pragma unroll
    for (int nb = 0; nb < 2; ++nb) {
        const int col = ncol0 + nb * 16 + l15;
        #pragma unroll
        for (int ks = 0; ks < 4; ++ks) {
            unsigned short t[8];
            #pragma unroll
            for (int jj = 0; jj < 8; ++jj)
                t[jj] = f2bf(W_enc[(size_t)(ks * 32 + g * 8 + jj) * EMB + col]);
            bfr[nb][ks] = *(bf16x8*)t;
        }
    }

    f32x4 acc[4][2];
    #pragma unroll
    for (int mb = 0; mb < 4; ++mb)
        #pragma unroll
        for (int nb = 0; nb < 2; ++nb)
            acc[mb][nb] = (f32x4){0.f, 0.f, 0.f, 0.f};

    __syncthreads();

    // ---- GEMM1: sA0 @ Wtop ----
    #pragma unroll
    for (int ks = 0; ks < 4; ++ks) {
        bf16x8 a[4];
        #pragma unroll
        for (int mb = 0; mb < 4; ++mb)
            a[mb] = *(const bf16x8*)&sA0[SWZ(mb * 16 + l15, ks * 32 + g * 8)];
        #pragma unroll
        for (int mb = 0; mb < 4; ++mb)
            #pragma unroll
            for (int nb = 0; nb < 2; ++nb)
                acc[mb][nb] = __builtin_amdgcn_mfma_f32_16x16x32_bf16(a[mb], bfr[nb][ks], acc[mb][nb], 0, 0, 0);
    }

    // epilogue 1: X = acc + bias; store Xb (pre-relu); relu into sA1
    #pragma unroll
    for (int mb = 0; mb < 4; ++mb) {
        #pragma unroll
        for (int nb = 0; nb < 2; ++nb) {
            const int col = ncol0 + nb * 16 + l15;
            const float bv = bias[col];
            #pragma unroll
            for (int r = 0; r < 4; ++r) {
                const int row_l = mb * 16 + g * 4 + r;
                float x = acc[mb][nb][r] + bv;
                Xb[(size_t)(block_row + row_l) * EMB + col] = f2bf(x);
                sA1[SWZ(row_l, col)] = f2bf(fmaxf(x, 0.f));
            }
            acc[mb][nb] = (f32x4){0.f, 0.f, 0.f, 0.f};
        }
    }
    __syncthreads();

    // B fragments for GEMM2 (Wbot, L2-hot) — loaded here to cut VGPR
    bf16x8 bfr2[2][4];
    #pragma unroll
    for (int nb = 0; nb < 2; ++nb) {
        const int col = ncol0 + nb * 16 + l15;
        #pragma unroll
        for (int ks = 0; ks < 4; ++ks) {
            unsigned short t[8];
            #pragma unroll
            for (int jj = 0; jj < 8; ++jj)
                t[jj] = f2bf(W_enc[(size_t)(128 + ks * 32 + g * 8 + jj) * EMB + col]);
            bfr2[nb][ks] = *(bf16x8*)t;
        }
    }

    // ---- GEMM2: relu(X) @ Wbot ----
    #pragma unroll
    for (int ks = 0; ks < 4; ++ks) {
        bf16x8 a[4];
        #pragma unroll
        for (int mb = 0; mb < 4; ++mb)
            a[mb] = *(const bf16x8*)&sA1[SWZ(mb * 16 + l15, ks * 32 + g * 8)];
        #pragma unroll
        for (int mb = 0; mb < 4; ++mb)
            #pragma unroll
            for (int nb = 0; nb < 2; ++nb)
                acc[mb][nb] = __builtin_amdgcn_mfma_f32_16x16x32_bf16(a[mb], bfr2[nb][ks], acc[mb][nb], 0, 0, 0);
    }
    #pragma unroll
    for (int mb = 0; mb < 4; ++mb)
        #pragma unroll
        for (int nb = 0; nb < 2; ++nb) {
            const int col = ncol0 + nb * 16 + l15;
            #pragma unroll
            for (int r = 0; r < 4; ++r) {
                const int row_l = mb * 16 + g * 4 + r;
                Yb[(size_t)(block_row + row_l) * EMB + col] = f2bf(acc[mb][nb][r]);
            }
        }
}

// ==== gather: R12 structure + wave-cooperative index broadcast ====
// Each wave's 8 n x 16 k = 128 neighbor indices are preloaded by TWO coalesced
// per-lane loads (flat[lane], flat[64+lane]) and extracted via v_readlane at
// compile-time lane positions (full unroll) -> SGPR indices, scalar-pipe Y-row
// address math. VMEM instrs per n drop 33 -> ~17 (the 16 per-lane redundant
// uniform-address idx loads disappear). Arithmetic values/order unchanged.
// In-block reduce -> chunk_pool[128] -> @W2 -> atomicAdd into out[b].
// XCD map: batch b on XCD b&7 (matches dual_gemm's producer map).
__global__ __launch_bounds__(256) void gather_pool_w2(const unsigned short* __restrict__ Xb,
                                                      const unsigned short* __restrict__ Yb,
                                                      const int*   __restrict__ nbr,
                                                      const float* __restrict__ mask,
                                                      const float* __restrict__ W2,
                                                      float* __restrict__ out)
{
    const int bid   = blockIdx.x;
    const int xcd   = bid & 7;
    const int rest  = bid >> 3;
    const int chunk = rest & 15;
    const int b     = (rest >> 4) * 8 + xcd;
    const int g     = threadIdx.x >> 6;        // 4 waves
    const int lane  = threadIdx.x & 63;

    const unsigned int* Yw = (const unsigned int*)(Yb + (size_t)b * N_SZ * EMB); // uniform
    const unsigned int* Xw = (const unsigned int*)Xb;                            // uniform

    // wave-cooperative preload of this wave's 128 neighbor indices (2 VMEM total)
    const int* flat = nbr + ((size_t)b * N_SZ + chunk * 32 + g * 8) * K_SZ;
    const int c0 = flat[lane];         // n 0..3  (k-major: n*16+k)
    const int c1 = flat[64 + lane];    // n 4..7

    float s0 = 0.f, s1 = 0.f;
    #pragma unroll
    for (int nn = 0; nn < 8; ++nn) {
        const unsigned int base = (unsigned int)(b * N_SZ + chunk * 32 + g * 8 + nn);

        float a0a = 0.f, a0b = 0.f, a1a = 0.f, a1b = 0.f;
        #pragma unroll
        for (int k = 0; k < K_SZ; k += 2) {
            const int fp0 = nn * K_SZ + k;       // compile-time lane position
            const int fp1 = fp0 + 1;
            const int id0 = (fp0 < 64) ? __builtin_amdgcn_readlane(c0, fp0)
                                       : __builtin_amdgcn_readlane(c1, fp0 - 64);
            const int id1 = (fp1 < 64) ? __builtin_amdgcn_readlane(c0, fp1)
                                       : __builtin_amdgcn_readlane(c1, fp1 - 64);
            unsigned int v0 = Yw[(((unsigned int)id0) << 6) + lane];
            unsigned int v1 = Yw[(((unsigned int)id1) << 6) + lane];
            a0a += bf_lo(v0); a1a += bf_hi(v0);
            a0b += bf_lo(v1); a1b += bf_hi(v1);
        }
        unsigned int xv = Xw[(base << 6) + lane];
        const float m = mask[base];
        s0 += fmaxf(bf_lo(xv) + (a0a + a0b) * 0.0625f, 0.f) * m;
        s1 += fmaxf(bf_hi(xv) + (a1a + a1b) * 0.0625f, 0.f) * m;
    }

    // in-block reduce: 4 wave-partials -> chunk_pool[128] in sred[0][*]
    __shared__ float sred[4][EMB];
    const int e0 = lane * 2;
    sred[g][e0]     = s0;
    sred[g][e0 + 1] = s1;
    __syncthreads();
    const int t = threadIdx.x;
    if (t < EMB)
        sred[0][t] = sred[0][t] + sred[1][t] + sred[2][t] + sred[3][t];
    __syncthreads();

    // chunk_pool @ W2 -> atomicAdd into out[b][*]
    if (t < EMB) {
        float r = 0.f;
        #pragma unroll 8
        for (int f = 0; f < EMB; ++f) r += sred[0][f] * W2[f * EMB + t];
        atomicAdd(&out[b * EMB + t], r);
    }
}

extern "C" void kernel_launch(void* const* d_in, const int* in_sizes, int n_in,
                              void* d_out, int out_size, void* d_ws, size_t ws_size,
                              hipStream_t stream)
{
    const float* word  = (const float*)d_in[0];
    const int*   nbr   = (const int*)  d_in[1];
    const float* mask  = (const float*)d_in[2];
    const float* W_enc = (const float*)d_in[3];
    const float* b_enc = (const float*)d_in[4];
    const float* W2    = (const float*)d_in[5];
    float* out = (float*)d_out;

    unsigned short* Xb = (unsigned short*)d_ws;          // [32768][128] bf16, 8 MB
    unsigned short* Yb = Xb + (size_t)R_TOT * EMB;       // 8 MB

    dual_gemm     <<<R_TOT / 64, 256, 0, stream>>>(word, W_enc, b_enc, Xb, Yb, out);
    gather_pool_w2<<<B_SZ * 16,  256, 0, stream>>>(Xb, Yb, nbr, mask, W2, out);
}